// Round 19
// baseline (621.064 us; speedup 1.0000x reference)
//
#include <hip/hip_runtime.h>
#include <cstdint>

typedef _Float16 half4v __attribute__((ext_vector_type(4)));
typedef _Float16 half8v __attribute__((ext_vector_type(8)));
typedef __fp16   fp16x2 __attribute__((ext_vector_type(2)));
typedef float    f32x4v __attribute__((ext_vector_type(4)));

#define DIM    4096
#define SEQ    2048
#define NBATCH 2
#define NHEAD  32
#define NKVH   8
#define HDIM   128
#define MROWS  (NBATCH*SEQ)   // 4096
#define QKV_N  6144           // weight rows: q(4096) | k(1024) | v(1024)
#define QKV_LD 5120           // activation row stride: q(4096) | k(1024); V goes to VT
#define KOFF   4096
#define VOFF   5120

// async global->LDS, 16B per lane; LDS dest is wave-uniform base + lane*16
__device__ __forceinline__ void gl_lds16(const void* g, void* l) {
  __builtin_amdgcn_global_load_lds(
      (const __attribute__((address_space(1))) void*)g,
      (__attribute__((address_space(3))) void*)l, 16, 0, 0);
}

// raw hardware exp2: single v_exp_f32 (VALU deps HW-interlocked on CDNA)
__device__ __forceinline__ float fexp2(float x) {
  float r;
  asm("v_exp_f32 %0, %1" : "=v"(r) : "v"(x));
  return r;
}

// 3-input max, single instruction (gfx9+)
__device__ __forceinline__ float fmax3(float a, float b, float c) {
  float r;
  asm("v_max3_f32 %0, %1, %2, %3" : "=v"(r) : "v"(a), "v"(b), "v"(c));
  return r;
}

// ---------------- fp32 -> fp16 convert ----------------
__global__ __launch_bounds__(256) void cvt_kernel(const float* __restrict__ in,
                                                  _Float16* __restrict__ out, int n8) {
  int stride = gridDim.x * blockDim.x;
  for (int i = blockIdx.x * blockDim.x + threadIdx.x; i < n8; i += stride) {
    const float4* p = (const float4*)(in + (size_t)i * 8);
    float4 a = p[0], b = p[1];
    half8v h;
    h[0] = (_Float16)a.x; h[1] = (_Float16)a.y; h[2] = (_Float16)a.z; h[3] = (_Float16)a.w;
    h[4] = (_Float16)b.x; h[5] = (_Float16)b.y; h[6] = (_Float16)b.z; h[7] = (_Float16)b.w;
    *(half8v*)(out + (size_t)i * 8) = h;
  }
}

// 3-source cvt into the contiguous wq|wk|wv fp16 block (one launch, 3 ranges)
__global__ __launch_bounds__(256) void cvt3_kernel(const float* __restrict__ s0,
                                                   const float* __restrict__ s1,
                                                   const float* __restrict__ s2,
                                                   _Float16* __restrict__ out) {
  const int n8 = (QKV_N * DIM) / 8;
  const size_t E1 = (size_t)KOFF * DIM;   // end of wq elems
  const size_t E2 = (size_t)VOFF * DIM;   // end of wk elems
  int stride = gridDim.x * blockDim.x;
  for (int i = blockIdx.x * blockDim.x + threadIdx.x; i < n8; i += stride) {
    size_t e = (size_t)i * 8;
    const float* src = (e < E1) ? (s0 + e) : (e < E2) ? (s1 + (e - E1)) : (s2 + (e - E2));
    const float4* p = (const float4*)src;
    float4 a = p[0], b = p[1];
    half8v h;
    h[0] = (_Float16)a.x; h[1] = (_Float16)a.y; h[2] = (_Float16)a.z; h[3] = (_Float16)a.w;
    h[4] = (_Float16)b.x; h[5] = (_Float16)b.y; h[6] = (_Float16)b.z; h[7] = (_Float16)b.w;
    *(half8v*)(out + e) = h;
  }
}

#define SBAR() do { asm volatile("" ::: "memory"); \
                    __builtin_amdgcn_s_barrier();  \
                    asm volatile("" ::: "memory"); } while (0)
#define LGK0() asm volatile("s_waitcnt lgkmcnt(0)" ::: "memory")
#define VM6()  asm volatile("s_waitcnt vmcnt(6)" ::: "memory")
#define VM4()  asm volatile("s_waitcnt vmcnt(4)" ::: "memory")
#define VM0()  asm volatile("s_waitcnt vmcnt(0)" ::: "memory")

// ---------------- shared GEMM phase machinery ----------------
#define STAGE_HALF(Gm, rowbase, kidx, h, buf) do {                                   \
    gl_lds16((Gm) + (size_t)((rowbase) + (h)*128 + srow) * K + (kidx)*64 + sslot8,   \
             (buf) + (h)*8192 + w*512);                                              \
    gl_lds16((Gm) + (size_t)((rowbase) + (h)*128 + 64 + srow) * K + (kidx)*64 + sslot8, \
             (buf) + (h)*8192 + 4096 + w*512);                                       \
  } while (0)

#define MFMA_Q(hm, hn, bf)                                                   \
    _Pragma("unroll") for (int kk = 0; kk < 2; ++kk)                         \
      _Pragma("unroll") for (int mi = 0; mi < 4; ++mi)                       \
        _Pragma("unroll") for (int ni = 0; ni < 2; ++ni)                     \
          acc[(hm) * 4 + mi][(hn) * 2 + ni] =                                \
              __builtin_amdgcn_mfma_f32_16x16x32_f16(                        \
                  a[mi][kk], bf[ni][kk], acc[(hm) * 4 + mi][(hn) * 2 + ni], 0, 0, 0)

#define KSTEP(kcur, AC, BC, AN)                                              \
  do {                                                                       \
    const int k_ = (kcur);                                                   \
    half8v a[4][2], b0[2][2], b1[2][2];                                      \
    /* ---- phase 1: quadrant (m0,n0) */                                     \
    _Pragma("unroll") for (int mi = 0; mi < 4; ++mi)                         \
      _Pragma("unroll") for (int kk = 0; kk < 2; ++kk)                       \
        a[mi][kk] = *(const half8v*)((AC) + (wm * 128 + mi * 16 + li) * 64 + \
                                     (((kk * 4 + g) ^ li7) * 8));            \
    _Pragma("unroll") for (int ni = 0; ni < 2; ++ni)                         \
      _Pragma("unroll") for (int kk = 0; kk < 2; ++kk)                       \
        b0[ni][kk] = *(const half8v*)((BC) + (wn * 64 + ni * 16 + li) * 64 + \
                                      (((kk * 4 + g) ^ li7) * 8));           \
    if (k_ + 1 < nkt) STAGE_HALF(A, bm, k_ + 1, 1, (AN));                    \
    SBAR(); LGK0();                                                          \
    __builtin_amdgcn_s_setprio(1);                                           \
    MFMA_Q(0, 0, b0);                                                        \
    __builtin_amdgcn_s_setprio(0);                                           \
    SBAR();                                                                  \
    /* ---- phase 2: quadrant (m0,n1) */                                     \
    _Pragma("unroll") for (int ni = 0; ni < 2; ++ni)                         \
      _Pragma("unroll") for (int kk = 0; kk < 2; ++kk)                       \
        b1[ni][kk] = *(const half8v*)((BC) + (wn * 64 + 32 + ni * 16 + li) * 64 + \
                                      (((kk * 4 + g) ^ li7) * 8));           \
    SBAR(); LGK0();                                                          \
    __builtin_amdgcn_s_setprio(1);                                           \
    MFMA_Q(0, 1, b1);                                                        \
    __builtin_amdgcn_s_setprio(0);                                           \
    SBAR();                                                                  \
    /* ---- phase 3: quadrant (m1,n1); stage B(k+2) into current buf */      \
    _Pragma("unroll") for (int mi = 0; mi < 4; ++mi)                         \
      _Pragma("unroll") for (int kk = 0; kk < 2; ++kk)                       \
        a[mi][kk] = *(const half8v*)((AC) + (wm * 128 + 64 + mi * 16 + li) * 64 + \
                                     (((kk * 4 + g) ^ li7) * 8));            \
    if (k_ + 2 < nkt) {                                                      \
      STAGE_HALF(B, bn, k_ + 2, 0, (BC));                                    \
      STAGE_HALF(B, bn, k_ + 2, 1, (BC));                                    \
    }                                                                        \
    SBAR(); LGK0();                                                          \
    __builtin_amdgcn_s_setprio(1);                                           \
    MFMA_Q(1, 1, b1);                                                        \
    __builtin_amdgcn_s_setprio(0);                                           \
    SBAR();                                                                  \
    /* ---- phase 4: quadrant (m1,n0); stage Ah0(k+2); counted vmcnt */      \
    if (k_ + 2 < nkt) STAGE_HALF(A, bm, k_ + 2, 0, (AC));                    \
    SBAR();                                                                  \
    __builtin_amdgcn_s_setprio(1);                                           \
    MFMA_Q(1, 0, b0);                                                        \
    __builtin_amdgcn_s_setprio(0);                                           \
    if (k_ + 2 < nkt) { VM6(); } else if (k_ + 1 < nkt) { VM0(); }           \
    SBAR();                                                                  \
  } while (0)

// half-tile (256x128) K-step: 2 barriers per 32 MFMA, A triple-buffered
#define HKSTEP2B(kcur, AC, BC, ASTG)                                         \
  do {                                                                       \
    const int k_ = (kcur);                                                   \
    half8v a[4][2], bb[2][2];                                                \
    _Pragma("unroll") for (int mi = 0; mi < 4; ++mi)                         \
      _Pragma("unroll") for (int kk = 0; kk < 2; ++kk)                       \
        a[mi][kk] = *(const half8v*)((AC) + (wm * 128 + mi * 16 + li) * 64 + \
                                     (((kk * 4 + g) ^ li7) * 8));            \
    _Pragma("unroll") for (int ni = 0; ni < 2; ++ni)                         \
      _Pragma("unroll") for (int kk = 0; kk < 2; ++kk)                       \
        bb[ni][kk] = *(const half8v*)((BC) + (wn * 32 + ni * 16 + li) * 64 + \
                                      (((kk * 4 + g) ^ li7) * 8));           \
    if (k_ + 2 < nkt) {                                                      \
      STAGE_HALF(A, bm2, k_ + 2, 0, (ASTG));                                 \
      STAGE_HALF(A, bm2, k_ + 2, 1, (ASTG));                                 \
    }                                                                        \
    LGK0();                                                                  \
    SBAR();                                                                  \
    if (k_ + 2 < nkt) STAGE_HALF(B, bn2, k_ + 2, 0, (BC));                   \
    __builtin_amdgcn_s_setprio(1);                                           \
    _Pragma("unroll") for (int kk = 0; kk < 2; ++kk)                         \
      _Pragma("unroll") for (int mi = 0; mi < 4; ++mi)                       \
        _Pragma("unroll") for (int ni = 0; ni < 2; ++ni)                     \
          acc2[mi][ni] = __builtin_amdgcn_mfma_f32_16x16x32_f16(             \
              a[mi][kk], bb[ni][kk], acc2[mi][ni], 0, 0, 0);                 \
    __builtin_amdgcn_s_setprio(0);                                           \
    _Pragma("unroll") for (int mi = 0; mi < 4; ++mi)                         \
      _Pragma("unroll") for (int kk = 0; kk < 2; ++kk)                       \
        a[mi][kk] = *(const half8v*)((AC) + (wm * 128 + 64 + mi * 16 + li) * 64 + \
                                     (((kk * 4 + g) ^ li7) * 8));            \
    __builtin_amdgcn_s_setprio(1);                                           \
    _Pragma("unroll") for (int kk = 0; kk < 2; ++kk)                         \
      _Pragma("unroll") for (int mi = 0; mi < 4; ++mi)                       \
        _Pragma("unroll") for (int ni = 0; ni < 2; ++ni)                     \
          acc2[4 + mi][ni] = __builtin_amdgcn_mfma_f32_16x16x32_f16(         \
              a[mi][kk], bb[ni][kk], acc2[4 + mi][ni], 0, 0, 0);             \
    __builtin_amdgcn_s_setprio(0);                                           \
    if (k_ + 2 < nkt) { VM6(); } else { VM0(); }                             \
    SBAR();                                                                  \
  } while (0)

// ---------------- GEMM 256x256 (proj): C[M,N] = A[M,K] * B[N,K]^T ----------------
template<int OUTF16>
__global__ __launch_bounds__(512, 2) void gemm256(const _Float16* __restrict__ A,
                                                  const _Float16* __restrict__ B,
                                                  void* __restrict__ Cp,
                                                  int N, int K, int nbx) {
  __shared__ __align__(16) _Float16 As[2][256 * 64];
  __shared__ __align__(16) _Float16 Bs[2][256 * 64];
  const int tid = threadIdx.x, lane = tid & 63, w = tid >> 6;
  const int g = lane >> 4, li = lane & 15, li7 = lane & 7;
  const int wm = w >> 2, wn = w & 3;
  const int nwg = gridDim.x, orig = blockIdx.x;
  const int wgid = (nwg & 7) ? orig : ((orig & 7) * (nwg >> 3) + (orig >> 3));
  const int bm = (wgid / nbx) * 256, bn = (wgid % nbx) * 256;
  const int srow = tid >> 3;
  const int sslot8 = ((lane & 7) ^ ((lane >> 3) & 7)) * 8;
  const int nkt = K >> 6;
  _Float16* As0 = &As[0][0]; _Float16* As1 = &As[1][0];
  _Float16* Bs0 = &Bs[0][0]; _Float16* Bs1 = &Bs[1][0];

  f32x4v acc[8][4] = {};

  STAGE_HALF(A, bm, 0, 0, As0);
  STAGE_HALF(A, bm, 0, 1, As0);
  STAGE_HALF(B, bn, 0, 0, Bs0);
  STAGE_HALF(B, bn, 0, 1, Bs0);
  if (nkt > 1) {
    STAGE_HALF(B, bn, 1, 0, Bs1);
    STAGE_HALF(B, bn, 1, 1, Bs1);
    STAGE_HALF(A, bm, 1, 0, As1);
    VM6();
  } else {
    VM0();
  }
  SBAR();

  for (int k = 0; k < nkt; k += 2) {
    KSTEP(k,     As0, Bs0, As1);
    KSTEP(k + 1, As1, Bs1, As0);
  }

  const int r0 = bm + wm * 128 + g * 4;
  const int c0 = bn + wn * 64 + li;
#pragma unroll
  for (int mi = 0; mi < 8; ++mi)
#pragma unroll
    for (int ni = 0; ni < 4; ++ni)
#pragma unroll
      for (int j = 0; j < 4; ++j) {
        size_t idx = (size_t)(r0 + mi * 16 + j) * N + (c0 + ni * 16);
        if (OUTF16) ((_Float16*)Cp)[idx] = (_Float16)acc[mi][ni][j];
        else        ((float*)Cp)[idx]    = acc[mi][ni][j];
      }
}

// ---------------- GEMM QKV: M=4096, N=6144, K=4096, grid 256, 1.5 tiles/block ----
// Q|K rows -> Cp (stride QKV_LD); V half-tiles transposed via LDS (coalesced
// 128B-per-thread stores) into VT[(b*NKVH+kvh)*128+hd][s].
__global__ __launch_bounds__(512, 2) void gemm_qkv(const _Float16* __restrict__ A,
                                                   const _Float16* __restrict__ B,
                                                   _Float16* __restrict__ Cp,
                                                   _Float16* __restrict__ Vt) {
  __shared__ __align__(16) _Float16 SH[4 * 16384];   // 128KB, carved below
  const int tid = threadIdx.x, lane = tid & 63, w = tid >> 6;
  const int g = lane >> 4, li = lane & 15, li7 = lane & 7;
  const int wm = w >> 2, wn = w & 3;
  const int K = DIM, nkt = DIM >> 6;
  const int orig = blockIdx.x;                       // grid 256 (%8==0)
  const int wgid = (orig & 7) * 32 + (orig >> 3);    // XCD swizzle
  const int bm = (wgid >> 4) * 256, bn = (wgid & 15) * 256;
  const int t2 = wgid >> 1;
  const int bm2 = (t2 >> 3) * 256;
  const int bn2 = (16 + (t2 & 7)) * 256 + (wgid & 1) * 128;
  const int srow = tid >> 3;
  const int sslot8 = ((lane & 7) ^ ((lane >> 3) & 7)) * 8;
  _Float16* As0 = SH;            _Float16* As1 = SH + 16384;
  _Float16* Bs0 = SH + 32768;    _Float16* Bs1 = SH + 49152;

  // ================= pass 1: full 256x256 tile (Q columns, stride QKV_LD) ======
  {
    f32x4v acc[8][4] = {};
    STAGE_HALF(A, bm, 0, 0, As0);
    STAGE_HALF(A, bm, 0, 1, As0);
    STAGE_HALF(B, bn, 0, 0, Bs0);
    STAGE_HALF(B, bn, 0, 1, Bs0);
    STAGE_HALF(B, bn, 1, 0, Bs1);
    STAGE_HALF(B, bn, 1, 1, Bs1);
    STAGE_HALF(A, bm, 1, 0, As1);
    VM6();
    SBAR();
    for (int k = 0; k < nkt; k += 2) {
      KSTEP(k,     As0, Bs0, As1);
      KSTEP(k + 1, As1, Bs1, As0);
    }
    const int r0 = bm + wm * 128 + g * 4;
    const int c0 = bn + wn * 64 + li;
#pragma unroll
    for (int mi = 0; mi < 8; ++mi)
#pragma unroll
      for (int ni = 0; ni < 4; ++ni)
#pragma unroll
        for (int j = 0; j < 4; ++j)
          Cp[(size_t)(r0 + mi * 16 + j) * QKV_LD + (c0 + ni * 16)] = (_Float16)acc[mi][ni][j];
  }

  // ---- pass-2 prologue: 12 loads AFTER stores; VM6 drains all stores +
  // A(0),B(0) (6 oldest loads), leaves A(1)+B(1) (6 newest) in flight.
  STAGE_HALF(A, bm2, 0, 0, As0);
  STAGE_HALF(A, bm2, 0, 1, As0);
  STAGE_HALF(B, bn2, 0, 0, Bs1);            // B(0) -> Bs1 lo half
  STAGE_HALF(A, bm2, 1, 0, As1);
  STAGE_HALF(A, bm2, 1, 1, As1);
  STAGE_HALF(B, bn2, 1, 0, Bs1 + 8192);     // B(1) -> Bs1 hi half
  VM6();
  SBAR();

  // ================= pass 2: half 256x128 tile (A triple-buffered, 2-barrier) ==
  {
    f32x4v acc2[8][2] = {};
    _Float16 *Ac = As0, *An1 = As1, *An2 = Bs0;       // A ring: k, k+1, k+2
    _Float16 *Bc = Bs1, *Bn = Bs1 + 8192;             // B ping-pong (16KB each)
    for (int k = 0; k < nkt; ++k) {
      HKSTEP2B(k, Ac, Bc, An2);
      _Float16* t = Ac; Ac = An1; An1 = An2; An2 = t;
      t = Bc; Bc = Bn; Bn = t;
    }
    if (bn2 >= VOFF) {
      // V half-tile: transpose via LDS (all buffers dead), coalesced store.
      // Block-uniform: kvh2, bb, sb (half-tiles are 128-col / 256-row aligned).
      const int kvh2 = (bn2 - VOFF) >> 7;
      const int bb = bm2 >> 11;
      const int sb = bm2 & (SEQ - 1);
      _Float16* T = SH;                         // [col][row], stride 264 halfs
      const int col0 = wn * 32 + li;
      const int row0 = wm * 128 + g * 4;
#pragma unroll
      for (int mi = 0; mi < 8; ++mi)
#pragma unroll
        for (int ni = 0; ni < 2; ++ni) {
          half4v hv;
          hv[0] = (_Float16)acc2[mi][ni][0];
          hv[1] = (_Float16)acc2[mi][ni][1];
          hv[2] = (_Float16)acc2[mi][ni][2];
          hv[3] = (_Float16)acc2[mi][ni][3];
          *(half4v*)(T + (col0 + ni * 16) * 264 + row0 + mi * 16) = hv;
        }
      SBAR();
      // thread t: hd = t>>2, s-chunk (t&3)*64 -> 128B contiguous global store
      const int hd = tid >> 2, sq = (tid & 3) * 64;
      _Float16* dst = Vt + ((size_t)((bb * NKVH + kvh2) * 128 + hd)) * SEQ + sb + sq;
      const _Float16* srcT = T + hd * 264 + sq;
#pragma unroll
      for (int j = 0; j < 64; j += 8)
        *(half8v*)(dst + j) = *(const half8v*)(srcT + j);
    } else {
      // K half-tile: normal store, stride QKV_LD (cols 4096..5119 fit)
      const int r0 = bm2 + wm * 128 + g * 4;
      const int c0 = bn2 + wn * 32 + li;
#pragma unroll
      for (int mi = 0; mi < 8; ++mi)
#pragma unroll
        for (int ni = 0; ni < 2; ++ni)
#pragma unroll
          for (int j = 0; j < 4; ++j)
            Cp[(size_t)(r0 + mi * 16 + j) * QKV_LD + (c0 + ni * 16)] = (_Float16)acc2[mi][ni][j];
    }
  }
}

// ---------------- fused LayerNorm+RoPE for Q and K ranges, one launch ----------------
template<int E>
__device__ __forceinline__ void ln_rope_row(_Float16* rp, int s,
                                            const float* gw, const float* gb,
                                            const float* fc, float qs,
                                            int tid, int lane, int w, float* red) {
  constexpr int EPT = E / 256;
  float v[EPT];
#pragma unroll
  for (int i = 0; i < EPT; i += 4) {
    half4v hv = *(const half4v*)(rp + i);
    v[i] = (float)hv[0]; v[i+1] = (float)hv[1]; v[i+2] = (float)hv[2]; v[i+3] = (float)hv[3];
  }
  float sum = 0.f, ssq = 0.f;
#pragma unroll
  for (int i = 0; i < EPT; ++i) { sum += v[i]; ssq += v[i] * v[i]; }
#pragma unroll
  for (int off = 1; off < 64; off <<= 1) { sum += __shfl_xor(sum, off); ssq += __shfl_xor(ssq, off); }
  if (lane == 0) { red[w] = sum; red[4 + w] = ssq; }
  __syncthreads();
  sum = red[0] + red[1] + red[2] + red[3];
  ssq = red[4] + red[5] + red[6] + red[7];
  const float mu = sum * (1.0f / E);
  const float rstd = rsqrtf(ssq * (1.0f / E) - mu * mu + 1e-5f);
  float ov[EPT];
#pragma unroll
  for (int i = 0; i < EPT; i += 2) {
    int e = tid * EPT + i;
    int hd = e & (HDIM - 1);
    float2 cs = *(const float2*)(fc + (size_t)s * HDIM + (hd >> 1) * 2);
    float a = (v[i]   - mu) * rstd * gw[e]   + gb[e];
    float b = (v[i+1] - mu) * rstd * gw[e+1] + gb[e+1];
    ov[i]   = (a * cs.x - b * cs.y) * qs;
    ov[i+1] = (a * cs.y + b * cs.x) * qs;
  }
#pragma unroll
  for (int i = 0; i < EPT; i += 4) {
    half4v hv;
    hv[0] = (_Float16)ov[i];   hv[1] = (_Float16)ov[i+1];
    hv[2] = (_Float16)ov[i+2]; hv[3] = (_Float16)ov[i+3];
    *(half4v*)(rp + i) = hv;
  }
}

__global__ __launch_bounds__(256) void ln_rope_fused(_Float16* __restrict__ t,
                                                     const float* __restrict__ qnw,
                                                     const float* __restrict__ qnb,
                                                     const float* __restrict__ knw,
                                                     const float* __restrict__ knb,
                                                     const float* __restrict__ fc,
                                                     float qs) {
  __shared__ float red[8];
  const int blk = blockIdx.x;
  const int tid = threadIdx.x, lane = tid & 63, w = tid >> 6;
  if (blk < MROWS) {
    const int row = blk, s = row & (SEQ - 1);
    ln_rope_row<4096>(t + (size_t)row * QKV_LD + tid * 16, s, qnw, qnb, fc, qs,
                      tid, lane, w, red);
  } else {
    const int row = blk - MROWS, s = row & (SEQ - 1);
    ln_rope_row<1024>(t + (size_t)row * QKV_LD + KOFF + tid * 4, s, knw, knb, fc, 1.0f,
                      tid, lane, w, red);
  }
}

// ---------------- Flash attention (proven 224.5us config: (256,2)) ----------------
__global__ __launch_bounds__(256, 2) void attn_kernel(const _Float16* __restrict__ QKV,
                                                      const _Float16* __restrict__ VT,
                                                      _Float16* __restrict__ Oa) {
  __shared__ __align__(16) _Float16 Ksh[2][64 * 128];  // row-swizzled K, dbuf (32KB)
  __shared__ __align__(16) char Vsh[128 * 128];        // V^T rows=hd, swz 16B slots (16KB)
  const int tid = threadIdx.x, lane = tid & 63, w = tid >> 6;   // w: 0..3
  const int g = lane >> 4, li = lane & 15;
  const int blk = blockIdx.x;
  const int qt = blk & 15, h = (blk >> 4) & 31, b = blk >> 9;
  const int kvh = h >> 2;
  const size_t LD = QKV_LD;
  const _Float16* Qb = QKV + (size_t)(b * SEQ) * LD + h * HDIM;
  const _Float16* Kb = QKV + (size_t)(b * SEQ) * LD + KOFF + kvh * HDIM;
  const _Float16* VTb = VT + (size_t)((b * NKVH + kvh) * 128) * SEQ;
  const int lg = lane >> 4;
  const int gbit = (lane >> 5) & 1;
  const float THR = 11.541560327111707f;   // 8 * log2(e)

  // Two Q sub-tiles per wave (Q pre-scaled in ln_rope)
  half8v qf[2][4];
#pragma unroll
  for (int s = 0; s < 2; ++s) {
    const int qrow = qt * 128 + w * 32 + s * 16 + li;
#pragma unroll
    for (int kk = 0; kk < 4; ++kk)
      qf[s][kk] = *(const half8v*)(Qb + (size_t)qrow * LD + kk * 32 + g * 8);
  }
  float mrow[2] = {-1e30f, -1e30f}, lrow[2] = {0.f, 0.f};
  f32x4v oacc[2][8] = {};

  // 16 K chunks over 4 waves: 4 gl_lds per wave
#define ASTAGE_K(kt_, buf_) do {                                              \
    _Pragma("unroll") for (int i_ = 0; i_ < 4; ++i_) {                        \
      int chunk = i_ * 4 + w;                                                 \
      int r = chunk * 4 + lg;                                                 \
      int sc8 = ((lane & 15) ^ (r & 7)) * 8;                                  \
      gl_lds16(Kb + (size_t)((kt_) * 64 + r) * LD + sc8, (buf_) + chunk * 512); \
    } } while (0)

#define ASTAGE_V(kt_, buf_) do {                                              \
    _Pragma("unroll") for (int i_ = 0; i_ < 4; ++i_) {                        \
      int chunk = i_ * 4 + w;                                                 \
      int hd_ = chunk * 8 + (lane >> 3);                                      \
      int keyh = (chunk ^ (lane >> 3)) & 7;                                   \
      int p_ = lane & 7;                                                      \
      gl_lds16(VTb + (size_t)hd_ * SEQ + (kt_) * 64 + ((p_ ^ keyh) * 8),      \
               (buf_) + chunk * 1024);                                        \
    } } while (0)

  // prologue: tile 0 fully resident
  ASTAGE_K(0, Ksh[0]);
  ASTAGE_V(0, Vsh);
  VM0();
  SBAR();

  const int NT = SEQ / 64;
  for (int kt = 0; kt < NT; ++kt) {
    const int cur = kt & 1;
    // ---- S^T = K Q^T : one kf read feeds both sub-tiles (log2 domain)
    const _Float16* Kcur = Ksh[cur];
    f32x4v sc0[4] = {}, sc1[4] = {};
    __builtin_amdgcn_s_setprio(1);
#pragma unroll
    for (int kk = 0; kk < 4; ++kk) {
#pragma unroll
      for (int ni = 0; ni < 4; ++ni) {
        half8v kf = *(const half8v*)(Kcur + (16 * ni + li) * 128 + ((4 * kk + g) ^ (li & 7)) * 8);
        sc0[ni] = __builtin_amdgcn_mfma_f32_16x16x32_f16(kf, qf[0][kk], sc0[ni], 0, 0, 0);
        sc1[ni] = __builtin_amdgcn_mfma_f32_16x16x32_f16(kf, qf[1][kk], sc1[ni], 0, 0, 0);
      }
    }
    __builtin_amdgcn_s_setprio(0);
    // ---- issue K[kt+1] prefetch (drained at end-of-tile VM0 + barrier A)
    if (kt + 1 < NT) ASTAGE_K(kt + 1, Ksh[cur ^ 1]);
    // ---- online softmax (log2 domain) with defer-max, per sub-tile
    uint32_t u[2][4][2];
#pragma unroll
    for (int s = 0; s < 2; ++s) {
      f32x4v* sc = s ? sc1 : sc0;
      float ma = fmax3(fmaxf(sc[0][0], sc[0][1]), sc[0][2], sc[0][3]);
      float mb = fmax3(fmaxf(sc[1][0], sc[1][1]), sc[1][2], sc[1][3]);
      float mc = fmax3(fmaxf(sc[2][0], sc[2][1]), sc[2][2], sc[2][3]);
      float md = fmax3(fmaxf(sc[3][0], sc[3][1]), sc[3][2], sc[3][3]);
      float m16 = fmax3(fmaxf(ma, mb), mc, md);
      m16 = fmaxf(m16, __shfl_xor(m16, 16));
      m16 = fmaxf(m16, __shfl_xor(m16, 32));
      if (!__all(m16 - mrow[s] <= THR)) {
        const float mn = fmaxf(mrow[s], m16);
        const float sfo = fexp2(mrow[s] - mn);
        mrow[s] = mn;
        lrow[s] *= sfo;
        float sfj[4];
#pragma unroll
        for (int j = 0; j < 4; ++j) sfj[j] = __shfl(sfo, (lane & 48) | (4 * g + j));
#pragma unroll
        for (int nio = 0; nio < 8; ++nio) {
          oacc[s][nio][0] *= sfj[0]; oacc[s][nio][1] *= sfj[1];
          oacc[s][nio][2] *= sfj[2]; oacc[s][nio][3] *= sfj[3];
        }
      }
      float rs = 0.f;
#pragma unroll
      for (int ni = 0; ni < 4; ++ni)
#pragma unroll
        for (int j = 0; j < 4; ++j) { float pv = fexp2(sc[ni][j] - mrow[s]); sc[ni][j] = pv; rs += pv; }
      rs += __shfl_xor(rs, 16); rs += __shfl_xor(rs, 32);
      lrow[s] += rs;
#pragma unroll
      for (int ni = 0; ni < 4; ++ni) {
        fp16x2 p0 = __builtin_amdgcn_cvt_pkrtz(sc[ni][0], sc[ni][1]);
        fp16x2 p1 = __builtin_amdgcn_cvt_pkrtz(sc[ni][2], sc[ni][3]);
        u[s][ni][0] = *(uint32_t*)&p0;
        u[s][ni][1] = *(uint32_t*)&p1;
      }
    }
    // ---- drain V[kt] (counted: leaves the 4 newer K[kt+1] loads in flight)
    if (kt + 1 < NT) { VM4(); } else { VM0(); }
    SBAR();   // barrier B: all waves' V[kt] visible in Vsh
    // ---- redistribute P into PV A-fragments; one bv read feeds both sub-tiles
#pragma unroll
    for (int kk = 0; kk < 2; ++kk) {
      half8v pa[2];
#pragma unroll
      for (int s = 0; s < 2; ++s) {
        uint32_t own0 = gbit ? u[s][2*kk+1][0] : u[s][2*kk][0];
        uint32_t own1 = gbit ? u[s][2*kk+1][1] : u[s][2*kk][1];
        uint32_t oth0 = gbit ? u[s][2*kk][0]   : u[s][2*kk+1][0];
        uint32_t oth1 = gbit ? u[s][2*kk][1]   : u[s][2*kk+1][1];
        uint32_t r16_0 = (uint32_t)__shfl_xor((int)own0, 16);
        uint32_t r16_1 = (uint32_t)__shfl_xor((int)own1, 16);
        uint32_t r32_0 = (uint32_t)__shfl_xor((int)oth0, 32);
        uint32_t r32_1 = (uint32_t)__shfl_xor((int)oth1, 32);
        uint32_t r48_0 = (uint32_t)__shfl_xor((int)oth0, 48);
        uint32_t r48_1 = (uint32_t)__shfl_xor((int)oth1, 48);
        uint32_t d0 = (g == 0) ? own0 : (g == 1) ? r48_0 : (g == 2) ? r32_0 : r16_0;
        uint32_t d1 = (g == 0) ? own1 : (g == 1) ? r48_1 : (g == 2) ? r32_1 : r16_1;
        uint32_t d2 = (g == 0) ? r16_0 : (g == 1) ? r32_0 : (g == 2) ? r48_0 : own0;
        uint32_t d3 = (g == 0) ? r16_1 : (g == 1) ? r32_1 : (g == 2) ? r48_1 : own1;
        union { uint32_t u4[4]; half8v hh; } pu;
        pu.u4[0] = d0; pu.u4[1] = d1; pu.u4[2] = d2; pu.u4[3] = d3;
        pa[s] = pu.hh;
      }
      __builtin_amdgcn_s_setprio(1);
#pragma unroll
      for (int nio = 0; nio < 8; ++nio) {
        int r = nio * 16 + li;
        int key = ((r >> 3) ^ r) & 7;
        half8v bv = *(const half8v*)(Vsh + r * 128 + (((kk * 4 + g) ^ key) << 4));
        oacc[0][nio] = __builtin_amdgcn_mfma_f32_16x16x32_f16(pa[0], bv, oacc[0][nio], 0, 0, 0);
        oacc[1][nio] = __builtin_amdgcn_mfma_f32_16x16x32_f16(pa[1], bv, oacc[1][nio], 0, 0, 0);
      }
      __builtin_amdgcn_s_setprio(0);
    }
    // ---- drain own K[kt+1]; barrier A: all done PV reads, K visible
    VM0();
    SBAR();
    // ---- issue V[kt+1] into the now-free Vsh (covered by next QK+softmax)
    if (kt + 1 < NT) ASTAGE_V(kt + 1, Vsh);
  }
#undef ASTAGE_K
#undef ASTAGE_V
  // ---- epilogue: O[q=4g+j][hd=16nio+li] / l[q], per sub-tile
#pragma unroll
  for (int s = 0; s < 2; ++s) {
    float rinv[4];
#pragma unroll
    for (int j = 0; j < 4; ++j)
      rinv[j] = 1.0f / __shfl(lrow[s], (lane & 48) | (4 * g + j));
    _Float16* Ob = Oa + (size_t)(b * SEQ + qt * 128 + w * 32 + s * 16) * DIM + h * HDIM;
#pragma unroll
    for (int j = 0; j < 4; ++j)
#pragma unroll
      for (int nio = 0; nio < 8; ++nio)
        Ob[(size_t)(4 * g + j) * DIM + nio * 16 + li] = (_Float16)(oacc[s][nio][j] * rinv[j]);
  }
}

// ---------------- launcher ----------------
extern "C" void kernel_launch(void* const* d_in, const int* in_sizes, int n_in,
                              void* d_out, int out_size, void* d_ws, size_t ws_size,
                              hipStream_t stream) {
  const float* x   = (const float*)d_in[0];
  const float* fc  = (const float*)d_in[1];
  const float* wq  = (const float*)d_in[2];
  const float* wk  = (const float*)d_in[3];
  const float* wv  = (const float*)d_in[4];
  const float* wo  = (const float*)d_in[5];
  const float* qnw = (const float*)d_in[6];
  const float* qnb = (const float*)d_in[7];
  const float* knw = (const float*)d_in[8];
  const float* knb = (const float*)d_in[9];
  float* out = (float*)d_out;
  (void)in_sizes; (void)n_in; (void)out_size;

  const size_t MB = 1024 * 1024;
  if (ws_size < 128 * MB) return;
  char* ws = (char*)d_ws;
  _Float16* x_h    = (_Float16*)(ws + 0);        // 32 MB [4096,4096]
  _Float16* wqkv_h = (_Float16*)(ws + 32 * MB);  // 48 MB [6144,4096] (wq|wk|wv)
  _Float16* qkv_h  = (_Float16*)(ws + 80 * MB);  // 40 MB [4096,5120] (q|k)
  _Float16* vt_h   = (_Float16*)(ws + 120 * MB); // 8 MB VT[b,kvh,hd,s]
  _Float16* wo_h   = wqkv_h;                     // 32 MB, reuse after QKV GEMM
  _Float16* ao_h   = x_h;                        // reuse after QKV GEMM

  cvt_kernel<<<2048, 256, 0, stream>>>(x, x_h, (MROWS * DIM) / 8);
  // wq|wk|wv -> contiguous wqkv_h in ONE launch
  cvt3_kernel<<<2048, 256, 0, stream>>>(wq, wk, wv, wqkv_h);

  // QKV GEMM: grid 256 perfect fill; Q|K -> qkv_h (stride 5120), V -> vt_h transposed
  gemm_qkv<<<256, 512, 0, stream>>>(x_h, wqkv_h, qkv_h, vt_h);

  cvt_kernel<<<2048, 256, 0, stream>>>(wo, wo_h, (DIM * DIM) / 8);

  // fused LN+RoPE for Q (scaled by 1/sqrt(HD)*log2e) and K, one launch
  const float qscale = (float)(0.08838834764831845 * 1.4426950408889634);
  ln_rope_fused<<<2 * MROWS, 256, 0, stream>>>(qkv_h, qnw, qnb, knw, knb, fc, qscale);

  // QBLK=128 (4 waves x 2 sub-tiles): grid = B * H * S/128 = 1024
  attn_kernel<<<NBATCH * NHEAD * (SEQ / 128), 256, 0, stream>>>(qkv_h, vt_h, ao_h);

  // out proj: M=4096, N=4096, K=4096 -> grid 16*16 = 256 = 1 full wave
  gemm256<0><<<(MROWS / 256) * (DIM / 256), 512, 0, stream>>>(ao_h, wo_h, out,
                                                              DIM, DIM, DIM / 256);
}

// Round 20
// 604.447 us; speedup vs baseline: 1.0275x; 1.0275x over previous
//
#include <hip/hip_runtime.h>
#include <cstdint>

typedef _Float16 half4v __attribute__((ext_vector_type(4)));
typedef _Float16 half8v __attribute__((ext_vector_type(8)));
typedef __fp16   fp16x2 __attribute__((ext_vector_type(2)));
typedef float    f32x4v __attribute__((ext_vector_type(4)));

#define DIM    4096
#define SEQ    2048
#define NBATCH 2
#define NHEAD  32
#define NKVH   8
#define HDIM   128
#define MROWS  (NBATCH*SEQ)   // 4096
#define QKV_N  6144           // weight rows: q(4096) | k(1024) | v(1024)
#define QKV_LD 5120           // activation row stride: q(4096) | k(1024); V goes to VT
#define KOFF   4096
#define VOFF   5120

// async global->LDS, 16B per lane; LDS dest is wave-uniform base + lane*16
__device__ __forceinline__ void gl_lds16(const void* g, void* l) {
  __builtin_amdgcn_global_load_lds(
      (const __attribute__((address_space(1))) void*)g,
      (__attribute__((address_space(3))) void*)l, 16, 0, 0);
}

// raw hardware exp2: single v_exp_f32 (VALU deps HW-interlocked on CDNA)
__device__ __forceinline__ float fexp2(float x) {
  float r;
  asm("v_exp_f32 %0, %1" : "=v"(r) : "v"(x));
  return r;
}

// 3-input max, single instruction (gfx9+)
__device__ __forceinline__ float fmax3(float a, float b, float c) {
  float r;
  asm("v_max3_f32 %0, %1, %2, %3" : "=v"(r) : "v"(a), "v"(b), "v"(c));
  return r;
}

// ---------------- fp32 -> fp16 convert ----------------
__global__ __launch_bounds__(256) void cvt_kernel(const float* __restrict__ in,
                                                  _Float16* __restrict__ out, int n8) {
  int stride = gridDim.x * blockDim.x;
  for (int i = blockIdx.x * blockDim.x + threadIdx.x; i < n8; i += stride) {
    const float4* p = (const float4*)(in + (size_t)i * 8);
    float4 a = p[0], b = p[1];
    half8v h;
    h[0] = (_Float16)a.x; h[1] = (_Float16)a.y; h[2] = (_Float16)a.z; h[3] = (_Float16)a.w;
    h[4] = (_Float16)b.x; h[5] = (_Float16)b.y; h[6] = (_Float16)b.z; h[7] = (_Float16)b.w;
    *(half8v*)(out + (size_t)i * 8) = h;
  }
}

// 3-source cvt into the contiguous wq|wk|wv fp16 block (one launch, 3 ranges)
__global__ __launch_bounds__(256) void cvt3_kernel(const float* __restrict__ s0,
                                                   const float* __restrict__ s1,
                                                   const float* __restrict__ s2,
                                                   _Float16* __restrict__ out) {
  const int n8 = (QKV_N * DIM) / 8;
  const size_t E1 = (size_t)KOFF * DIM;   // end of wq elems
  const size_t E2 = (size_t)VOFF * DIM;   // end of wk elems
  int stride = gridDim.x * blockDim.x;
  for (int i = blockIdx.x * blockDim.x + threadIdx.x; i < n8; i += stride) {
    size_t e = (size_t)i * 8;
    const float* src = (e < E1) ? (s0 + e) : (e < E2) ? (s1 + (e - E1)) : (s2 + (e - E2));
    const float4* p = (const float4*)src;
    float4 a = p[0], b = p[1];
    half8v h;
    h[0] = (_Float16)a.x; h[1] = (_Float16)a.y; h[2] = (_Float16)a.z; h[3] = (_Float16)a.w;
    h[4] = (_Float16)b.x; h[5] = (_Float16)b.y; h[6] = (_Float16)b.z; h[7] = (_Float16)b.w;
    *(half8v*)(out + e) = h;
  }
}

#define SBAR() do { asm volatile("" ::: "memory"); \
                    __builtin_amdgcn_s_barrier();  \
                    asm volatile("" ::: "memory"); } while (0)
#define LGK0() asm volatile("s_waitcnt lgkmcnt(0)" ::: "memory")
#define VM6()  asm volatile("s_waitcnt vmcnt(6)" ::: "memory")
#define VM4()  asm volatile("s_waitcnt vmcnt(4)" ::: "memory")
#define VM0()  asm volatile("s_waitcnt vmcnt(0)" ::: "memory")

// ---------------- shared GEMM phase machinery ----------------
#define STAGE_HALF(Gm, rowbase, kidx, h, buf) do {                                   \
    gl_lds16((Gm) + (size_t)((rowbase) + (h)*128 + srow) * K + (kidx)*64 + sslot8,   \
             (buf) + (h)*8192 + w*512);                                              \
    gl_lds16((Gm) + (size_t)((rowbase) + (h)*128 + 64 + srow) * K + (kidx)*64 + sslot8, \
             (buf) + (h)*8192 + 4096 + w*512);                                       \
  } while (0)

#define MFMA_Q(hm, hn, bf)                                                   \
    _Pragma("unroll") for (int kk = 0; kk < 2; ++kk)                         \
      _Pragma("unroll") for (int mi = 0; mi < 4; ++mi)                       \
        _Pragma("unroll") for (int ni = 0; ni < 2; ++ni)                     \
          acc[(hm) * 4 + mi][(hn) * 2 + ni] =                                \
              __builtin_amdgcn_mfma_f32_16x16x32_f16(                        \
                  a[mi][kk], bf[ni][kk], acc[(hm) * 4 + mi][(hn) * 2 + ni], 0, 0, 0)

#define KSTEP(kcur, AC, BC, AN)                                              \
  do {                                                                       \
    const int k_ = (kcur);                                                   \
    half8v a[4][2], b0[2][2], b1[2][2];                                      \
    /* ---- phase 1: quadrant (m0,n0) */                                     \
    _Pragma("unroll") for (int mi = 0; mi < 4; ++mi)                         \
      _Pragma("unroll") for (int kk = 0; kk < 2; ++kk)                       \
        a[mi][kk] = *(const half8v*)((AC) + (wm * 128 + mi * 16 + li) * 64 + \
                                     (((kk * 4 + g) ^ li7) * 8));            \
    _Pragma("unroll") for (int ni = 0; ni < 2; ++ni)                         \
      _Pragma("unroll") for (int kk = 0; kk < 2; ++kk)                       \
        b0[ni][kk] = *(const half8v*)((BC) + (wn * 64 + ni * 16 + li) * 64 + \
                                      (((kk * 4 + g) ^ li7) * 8));           \
    if (k_ + 1 < nkt) STAGE_HALF(A, bm, k_ + 1, 1, (AN));                    \
    SBAR(); LGK0();                                                          \
    __builtin_amdgcn_s_setprio(1);                                           \
    MFMA_Q(0, 0, b0);                                                        \
    __builtin_amdgcn_s_setprio(0);                                           \
    SBAR();                                                                  \
    /* ---- phase 2: quadrant (m0,n1) */                                     \
    _Pragma("unroll") for (int ni = 0; ni < 2; ++ni)                         \
      _Pragma("unroll") for (int kk = 0; kk < 2; ++kk)                       \
        b1[ni][kk] = *(const half8v*)((BC) + (wn * 64 + 32 + ni * 16 + li) * 64 + \
                                      (((kk * 4 + g) ^ li7) * 8));           \
    SBAR(); LGK0();                                                          \
    __builtin_amdgcn_s_setprio(1);                                           \
    MFMA_Q(0, 1, b1);                                                        \
    __builtin_amdgcn_s_setprio(0);                                           \
    SBAR();                                                                  \
    /* ---- phase 3: quadrant (m1,n1); stage B(k+2) into current buf */      \
    _Pragma("unroll") for (int mi = 0; mi < 4; ++mi)                         \
      _Pragma("unroll") for (int kk = 0; kk < 2; ++kk)                       \
        a[mi][kk] = *(const half8v*)((AC) + (wm * 128 + 64 + mi * 16 + li) * 64 + \
                                     (((kk * 4 + g) ^ li7) * 8));            \
    if (k_ + 2 < nkt) {                                                      \
      STAGE_HALF(B, bn, k_ + 2, 0, (BC));                                    \
      STAGE_HALF(B, bn, k_ + 2, 1, (BC));                                    \
    }                                                                        \
    SBAR(); LGK0();                                                          \
    __builtin_amdgcn_s_setprio(1);                                           \
    MFMA_Q(1, 1, b1);                                                        \
    __builtin_amdgcn_s_setprio(0);                                           \
    SBAR();                                                                  \
    /* ---- phase 4: quadrant (m1,n0); stage Ah0(k+2); counted vmcnt */      \
    if (k_ + 2 < nkt) STAGE_HALF(A, bm, k_ + 2, 0, (AC));                    \
    SBAR();                                                                  \
    __builtin_amdgcn_s_setprio(1);                                           \
    MFMA_Q(1, 0, b0);                                                        \
    __builtin_amdgcn_s_setprio(0);                                           \
    if (k_ + 2 < nkt) { VM6(); } else if (k_ + 1 < nkt) { VM0(); }           \
    SBAR();                                                                  \
  } while (0)

// half-tile (256x128) K-step: 2 barriers per 32 MFMA, A triple-buffered
#define HKSTEP2B(kcur, AC, BC, ASTG)                                         \
  do {                                                                       \
    const int k_ = (kcur);                                                   \
    half8v a[4][2], bb[2][2];                                                \
    _Pragma("unroll") for (int mi = 0; mi < 4; ++mi)                         \
      _Pragma("unroll") for (int kk = 0; kk < 2; ++kk)                       \
        a[mi][kk] = *(const half8v*)((AC) + (wm * 128 + mi * 16 + li) * 64 + \
                                     (((kk * 4 + g) ^ li7) * 8));            \
    _Pragma("unroll") for (int ni = 0; ni < 2; ++ni)                         \
      _Pragma("unroll") for (int kk = 0; kk < 2; ++kk)                       \
        bb[ni][kk] = *(const half8v*)((BC) + (wn * 32 + ni * 16 + li) * 64 + \
                                      (((kk * 4 + g) ^ li7) * 8));           \
    if (k_ + 2 < nkt) {                                                      \
      STAGE_HALF(A, bm2, k_ + 2, 0, (ASTG));                                 \
      STAGE_HALF(A, bm2, k_ + 2, 1, (ASTG));                                 \
    }                                                                        \
    LGK0();                                                                  \
    SBAR();                                                                  \
    if (k_ + 2 < nkt) STAGE_HALF(B, bn2, k_ + 2, 0, (BC));                   \
    __builtin_amdgcn_s_setprio(1);                                           \
    _Pragma("unroll") for (int kk = 0; kk < 2; ++kk)                         \
      _Pragma("unroll") for (int mi = 0; mi < 4; ++mi)                       \
        _Pragma("unroll") for (int ni = 0; ni < 2; ++ni)                     \
          acc2[mi][ni] = __builtin_amdgcn_mfma_f32_16x16x32_f16(             \
              a[mi][kk], bb[ni][kk], acc2[mi][ni], 0, 0, 0);                 \
    __builtin_amdgcn_s_setprio(0);                                           \
    _Pragma("unroll") for (int mi = 0; mi < 4; ++mi)                         \
      _Pragma("unroll") for (int kk = 0; kk < 2; ++kk)                       \
        a[mi][kk] = *(const half8v*)((AC) + (wm * 128 + 64 + mi * 16 + li) * 64 + \
                                     (((kk * 4 + g) ^ li7) * 8));            \
    __builtin_amdgcn_s_setprio(1);                                           \
    _Pragma("unroll") for (int kk = 0; kk < 2; ++kk)                         \
      _Pragma("unroll") for (int mi = 0; mi < 4; ++mi)                       \
        _Pragma("unroll") for (int ni = 0; ni < 2; ++ni)                     \
          acc2[4 + mi][ni] = __builtin_amdgcn_mfma_f32_16x16x32_f16(         \
              a[mi][kk], bb[ni][kk], acc2[4 + mi][ni], 0, 0, 0);             \
    __builtin_amdgcn_s_setprio(0);                                           \
    if (k_ + 2 < nkt) { VM6(); } else { VM0(); }                             \
    SBAR();                                                                  \
  } while (0)

// ---------------- GEMM 256x256 (proj): C[M,N] = A[M,K] * B[N,K]^T ----------------
template<int OUTF16>
__global__ __launch_bounds__(512, 2) void gemm256(const _Float16* __restrict__ A,
                                                  const _Float16* __restrict__ B,
                                                  void* __restrict__ Cp,
                                                  int N, int K, int nbx) {
  __shared__ __align__(16) _Float16 As[2][256 * 64];
  __shared__ __align__(16) _Float16 Bs[2][256 * 64];
  const int tid = threadIdx.x, lane = tid & 63, w = tid >> 6;
  const int g = lane >> 4, li = lane & 15, li7 = lane & 7;
  const int wm = w >> 2, wn = w & 3;
  const int nwg = gridDim.x, orig = blockIdx.x;
  const int wgid = (nwg & 7) ? orig : ((orig & 7) * (nwg >> 3) + (orig >> 3));
  const int bm = (wgid / nbx) * 256, bn = (wgid % nbx) * 256;
  const int srow = tid >> 3;
  const int sslot8 = ((lane & 7) ^ ((lane >> 3) & 7)) * 8;
  const int nkt = K >> 6;
  _Float16* As0 = &As[0][0]; _Float16* As1 = &As[1][0];
  _Float16* Bs0 = &Bs[0][0]; _Float16* Bs1 = &Bs[1][0];

  f32x4v acc[8][4] = {};

  STAGE_HALF(A, bm, 0, 0, As0);
  STAGE_HALF(A, bm, 0, 1, As0);
  STAGE_HALF(B, bn, 0, 0, Bs0);
  STAGE_HALF(B, bn, 0, 1, Bs0);
  if (nkt > 1) {
    STAGE_HALF(B, bn, 1, 0, Bs1);
    STAGE_HALF(B, bn, 1, 1, Bs1);
    STAGE_HALF(A, bm, 1, 0, As1);
    VM6();
  } else {
    VM0();
  }
  SBAR();

  for (int k = 0; k < nkt; k += 2) {
    KSTEP(k,     As0, Bs0, As1);
    KSTEP(k + 1, As1, Bs1, As0);
  }

  const int r0 = bm + wm * 128 + g * 4;
  const int c0 = bn + wn * 64 + li;
#pragma unroll
  for (int mi = 0; mi < 8; ++mi)
#pragma unroll
    for (int ni = 0; ni < 4; ++ni)
#pragma unroll
      for (int j = 0; j < 4; ++j) {
        size_t idx = (size_t)(r0 + mi * 16 + j) * N + (c0 + ni * 16);
        if (OUTF16) ((_Float16*)Cp)[idx] = (_Float16)acc[mi][ni][j];
        else        ((float*)Cp)[idx]    = acc[mi][ni][j];
      }
}

// ---------------- GEMM QKV: M=4096, N=6144, K=4096, grid 256, 1.5 tiles/block ----
// C layout: Q|K rows with stride QKV_LD (5120); V half-tiles stored TRANSPOSED
// directly into VT[(b*NKVH+kvh)*128+hd][s] (vtrans kernel eliminated).
__global__ __launch_bounds__(512, 2) void gemm_qkv(const _Float16* __restrict__ A,
                                                   const _Float16* __restrict__ B,
                                                   _Float16* __restrict__ Cp,
                                                   _Float16* __restrict__ Vt) {
  __shared__ __align__(16) _Float16 As[2][256 * 64];
  __shared__ __align__(16) _Float16 Bs[2][256 * 64];
  const int tid = threadIdx.x, lane = tid & 63, w = tid >> 6;
  const int g = lane >> 4, li = lane & 15, li7 = lane & 7;
  const int wm = w >> 2, wn = w & 3;
  const int K = DIM, nkt = DIM >> 6;
  const int orig = blockIdx.x;                       // grid 256 (%8==0)
  const int wgid = (orig & 7) * 32 + (orig >> 3);    // XCD swizzle
  const int bm = (wgid >> 4) * 256, bn = (wgid & 15) * 256;
  const int t2 = wgid >> 1;
  const int bm2 = (t2 >> 3) * 256;
  const int bn2 = (16 + (t2 & 7)) * 256 + (wgid & 1) * 128;
  const int srow = tid >> 3;
  const int sslot8 = ((lane & 7) ^ ((lane >> 3) & 7)) * 8;
  _Float16* As0 = &As[0][0]; _Float16* As1 = &As[1][0];
  _Float16* Bs0 = &Bs[0][0]; _Float16* Bs1 = &Bs[1][0];

  // ================= pass 1: full 256x256 tile (Q columns, stride QKV_LD) ======
  {
    f32x4v acc[8][4] = {};
    STAGE_HALF(A, bm, 0, 0, As0);
    STAGE_HALF(A, bm, 0, 1, As0);
    STAGE_HALF(B, bn, 0, 0, Bs0);
    STAGE_HALF(B, bn, 0, 1, Bs0);
    STAGE_HALF(B, bn, 1, 0, Bs1);
    STAGE_HALF(B, bn, 1, 1, Bs1);
    STAGE_HALF(A, bm, 1, 0, As1);
    VM6();
    SBAR();
    for (int k = 0; k < nkt; k += 2) {
      KSTEP(k,     As0, Bs0, As1);
      KSTEP(k + 1, As1, Bs1, As0);
    }
    const int r0 = bm + wm * 128 + g * 4;
    const int c0 = bn + wn * 64 + li;
#pragma unroll
    for (int mi = 0; mi < 8; ++mi)
#pragma unroll
      for (int ni = 0; ni < 4; ++ni)
#pragma unroll
        for (int j = 0; j < 4; ++j)
          Cp[(size_t)(r0 + mi * 16 + j) * QKV_LD + (c0 + ni * 16)] = (_Float16)acc[mi][ni][j];
  }

  // ---- pass-2 prologue: 12 loads AFTER stores; VM6 drains all stores +
  // A(0),B(0) (6 oldest loads), leaves A(1)+B(1) (6 newest) in flight.
  STAGE_HALF(A, bm2, 0, 0, As0);
  STAGE_HALF(A, bm2, 0, 1, As0);
  STAGE_HALF(B, bn2, 0, 0, Bs1);            // B(0) -> Bs1 lo half
  STAGE_HALF(A, bm2, 1, 0, As1);
  STAGE_HALF(A, bm2, 1, 1, As1);
  STAGE_HALF(B, bn2, 1, 0, Bs1 + 8192);     // B(1) -> Bs1 hi half
  VM6();
  SBAR();

  // ================= pass 2: half 256x128 tile (A triple-buffered, 2-barrier) ==
  {
    f32x4v acc2[8][2] = {};
    _Float16 *Ac = As0, *An1 = As1, *An2 = Bs0;       // A ring: k, k+1, k+2
    _Float16 *Bc = Bs1, *Bn = Bs1 + 8192;             // B ping-pong (16KB each)
    for (int k = 0; k < nkt; ++k) {
      HKSTEP2B(k, Ac, Bc, An2);
      _Float16* t = Ac; Ac = An1; An1 = An2; An2 = t;
      t = Bc; Bc = Bn; Bn = t;
    }
    if (bn2 >= VOFF) {
      // V half-tile: store transposed into VT[(b*NKVH+kvh)*128+hd][s], 8B chunks
      const int colb = bn2 - VOFF + wn * 32 + li;
      const int rowb = bm2 + wm * 128 + g * 4;
#pragma unroll
      for (int mi = 0; mi < 8; ++mi)
#pragma unroll
        for (int ni = 0; ni < 2; ++ni) {
          int col = colb + ni * 16;
          int kvh2 = col >> 7, hdl = col & 127;
          int row = rowb + mi * 16;
          int bb = row >> 11, s = row & (SEQ - 1);
          half4v hv;
          hv[0] = (_Float16)acc2[mi][ni][0];
          hv[1] = (_Float16)acc2[mi][ni][1];
          hv[2] = (_Float16)acc2[mi][ni][2];
          hv[3] = (_Float16)acc2[mi][ni][3];
          *(half4v*)(Vt + ((size_t)((bb * NKVH + kvh2) * 128 + hdl)) * SEQ + s) = hv;
        }
    } else {
      // K half-tile: normal store, stride QKV_LD (cols 4096..5119 fit)
      const int r0 = bm2 + wm * 128 + g * 4;
      const int c0 = bn2 + wn * 32 + li;
#pragma unroll
      for (int mi = 0; mi < 8; ++mi)
#pragma unroll
        for (int ni = 0; ni < 2; ++ni)
#pragma unroll
          for (int j = 0; j < 4; ++j)
            Cp[(size_t)(r0 + mi * 16 + j) * QKV_LD + (c0 + ni * 16)] = (_Float16)acc2[mi][ni][j];
    }
  }
}

// ---------------- fused LayerNorm+RoPE for Q and K ranges, one launch ----------------
template<int E>
__device__ __forceinline__ void ln_rope_row(_Float16* rp, int s,
                                            const float* gw, const float* gb,
                                            const float* fc, float qs,
                                            int tid, int lane, int w, float* red) {
  constexpr int EPT = E / 256;
  float v[EPT];
#pragma unroll
  for (int i = 0; i < EPT; i += 4) {
    half4v hv = *(const half4v*)(rp + i);
    v[i] = (float)hv[0]; v[i+1] = (float)hv[1]; v[i+2] = (float)hv[2]; v[i+3] = (float)hv[3];
  }
  float sum = 0.f, ssq = 0.f;
#pragma unroll
  for (int i = 0; i < EPT; ++i) { sum += v[i]; ssq += v[i] * v[i]; }
#pragma unroll
  for (int off = 1; off < 64; off <<= 1) { sum += __shfl_xor(sum, off); ssq += __shfl_xor(ssq, off); }
  if (lane == 0) { red[w] = sum; red[4 + w] = ssq; }
  __syncthreads();
  sum = red[0] + red[1] + red[2] + red[3];
  ssq = red[4] + red[5] + red[6] + red[7];
  const float mu = sum * (1.0f / E);
  const float rstd = rsqrtf(ssq * (1.0f / E) - mu * mu + 1e-5f);
  float ov[EPT];
#pragma unroll
  for (int i = 0; i < EPT; i += 2) {
    int e = tid * EPT + i;
    int hd = e & (HDIM - 1);
    float2 cs = *(const float2*)(fc + (size_t)s * HDIM + (hd >> 1) * 2);
    float a = (v[i]   - mu) * rstd * gw[e]   + gb[e];
    float b = (v[i+1] - mu) * rstd * gw[e+1] + gb[e+1];
    ov[i]   = (a * cs.x - b * cs.y) * qs;
    ov[i+1] = (a * cs.y + b * cs.x) * qs;
  }
#pragma unroll
  for (int i = 0; i < EPT; i += 4) {
    half4v hv;
    hv[0] = (_Float16)ov[i];   hv[1] = (_Float16)ov[i+1];
    hv[2] = (_Float16)ov[i+2]; hv[3] = (_Float16)ov[i+3];
    *(half4v*)(rp + i) = hv;
  }
}

__global__ __launch_bounds__(256) void ln_rope_fused(_Float16* __restrict__ t,
                                                     const float* __restrict__ qnw,
                                                     const float* __restrict__ qnb,
                                                     const float* __restrict__ knw,
                                                     const float* __restrict__ knb,
                                                     const float* __restrict__ fc,
                                                     float qs) {
  __shared__ float red[8];
  const int blk = blockIdx.x;
  const int tid = threadIdx.x, lane = tid & 63, w = tid >> 6;
  if (blk < MROWS) {
    const int row = blk, s = row & (SEQ - 1);
    ln_rope_row<4096>(t + (size_t)row * QKV_LD + tid * 16, s, qnw, qnb, fc, qs,
                      tid, lane, w, red);
  } else {
    const int row = blk - MROWS, s = row & (SEQ - 1);
    ln_rope_row<1024>(t + (size_t)row * QKV_LD + KOFF + tid * 4, s, knw, knb, fc, 1.0f,
                      tid, lane, w, red);
  }
}

// ---------------- Flash attention (proven 224.5us config: (256,2)) ----------------
__global__ __launch_bounds__(256, 2) void attn_kernel(const _Float16* __restrict__ QKV,
                                                      const _Float16* __restrict__ VT,
                                                      _Float16* __restrict__ Oa) {
  __shared__ __align__(16) _Float16 Ksh[2][64 * 128];  // row-swizzled K, dbuf (32KB)
  __shared__ __align__(16) char Vsh[128 * 128];        // V^T rows=hd, swz 16B slots (16KB)
  const int tid = threadIdx.x, lane = tid & 63, w = tid >> 6;   // w: 0..3
  const int g = lane >> 4, li = lane & 15;
  const int blk = blockIdx.x;
  const int qt = blk & 15, h = (blk >> 4) & 31, b = blk >> 9;
  const int kvh = h >> 2;
  const size_t LD = QKV_LD;
  const _Float16* Qb = QKV + (size_t)(b * SEQ) * LD + h * HDIM;
  const _Float16* Kb = QKV + (size_t)(b * SEQ) * LD + KOFF + kvh * HDIM;
  const _Float16* VTb = VT + (size_t)((b * NKVH + kvh) * 128) * SEQ;
  const int lg = lane >> 4;
  const int gbit = (lane >> 5) & 1;
  const float THR = 11.541560327111707f;   // 8 * log2(e)

  // Two Q sub-tiles per wave (Q pre-scaled in ln_rope)
  half8v qf[2][4];
#pragma unroll
  for (int s = 0; s < 2; ++s) {
    const int qrow = qt * 128 + w * 32 + s * 16 + li;
#pragma unroll
    for (int kk = 0; kk < 4; ++kk)
      qf[s][kk] = *(const half8v*)(Qb + (size_t)qrow * LD + kk * 32 + g * 8);
  }
  float mrow[2] = {-1e30f, -1e30f}, lrow[2] = {0.f, 0.f};
  f32x4v oacc[2][8] = {};

  // 16 K chunks over 4 waves: 4 gl_lds per wave
#define ASTAGE_K(kt_, buf_) do {                                              \
    _Pragma("unroll") for (int i_ = 0; i_ < 4; ++i_) {                        \
      int chunk = i_ * 4 + w;                                                 \
      int r = chunk * 4 + lg;                                                 \
      int sc8 = ((lane & 15) ^ (r & 7)) * 8;                                  \
      gl_lds16(Kb + (size_t)((kt_) * 64 + r) * LD + sc8, (buf_) + chunk * 512); \
    } } while (0)

#define ASTAGE_V(kt_, buf_) do {                                              \
    _Pragma("unroll") for (int i_ = 0; i_ < 4; ++i_) {                        \
      int chunk = i_ * 4 + w;                                                 \
      int hd_ = chunk * 8 + (lane >> 3);                                      \
      int keyh = (chunk ^ (lane >> 3)) & 7;                                   \
      int p_ = lane & 7;                                                      \
      gl_lds16(VTb + (size_t)hd_ * SEQ + (kt_) * 64 + ((p_ ^ keyh) * 8),      \
               (buf_) + chunk * 1024);                                        \
    } } while (0)

  // prologue: tile 0 fully resident
  ASTAGE_K(0, Ksh[0]);
  ASTAGE_V(0, Vsh);
  VM0();
  SBAR();

  const int NT = SEQ / 64;
  for (int kt = 0; kt < NT; ++kt) {
    const int cur = kt & 1;
    // ---- S^T = K Q^T : one kf read feeds both sub-tiles (log2 domain)
    const _Float16* Kcur = Ksh[cur];
    f32x4v sc0[4] = {}, sc1[4] = {};
    __builtin_amdgcn_s_setprio(1);
#pragma unroll
    for (int kk = 0; kk < 4; ++kk) {
#pragma unroll
      for (int ni = 0; ni < 4; ++ni) {
        half8v kf = *(const half8v*)(Kcur + (16 * ni + li) * 128 + ((4 * kk + g) ^ (li & 7)) * 8);
        sc0[ni] = __builtin_amdgcn_mfma_f32_16x16x32_f16(kf, qf[0][kk], sc0[ni], 0, 0, 0);
        sc1[ni] = __builtin_amdgcn_mfma_f32_16x16x32_f16(kf, qf[1][kk], sc1[ni], 0, 0, 0);
      }
    }
    __builtin_amdgcn_s_setprio(0);
    // ---- issue K[kt+1] prefetch (drained at end-of-tile VM0 + barrier A)
    if (kt + 1 < NT) ASTAGE_K(kt + 1, Ksh[cur ^ 1]);
    // ---- online softmax (log2 domain) with defer-max, per sub-tile
    uint32_t u[2][4][2];
#pragma unroll
    for (int s = 0; s < 2; ++s) {
      f32x4v* sc = s ? sc1 : sc0;
      float ma = fmax3(fmaxf(sc[0][0], sc[0][1]), sc[0][2], sc[0][3]);
      float mb = fmax3(fmaxf(sc[1][0], sc[1][1]), sc[1][2], sc[1][3]);
      float mc = fmax3(fmaxf(sc[2][0], sc[2][1]), sc[2][2], sc[2][3]);
      float md = fmax3(fmaxf(sc[3][0], sc[3][1]), sc[3][2], sc[3][3]);
      float m16 = fmax3(fmaxf(ma, mb), mc, md);
      m16 = fmaxf(m16, __shfl_xor(m16, 16));
      m16 = fmaxf(m16, __shfl_xor(m16, 32));
      if (!__all(m16 - mrow[s] <= THR)) {
        const float mn = fmaxf(mrow[s], m16);
        const float sfo = fexp2(mrow[s] - mn);
        mrow[s] = mn;
        lrow[s] *= sfo;
        float sfj[4];
#pragma unroll
        for (int j = 0; j < 4; ++j) sfj[j] = __shfl(sfo, (lane & 48) | (4 * g + j));
#pragma unroll
        for (int nio = 0; nio < 8; ++nio) {
          oacc[s][nio][0] *= sfj[0]; oacc[s][nio][1] *= sfj[1];
          oacc[s][nio][2] *= sfj[2]; oacc[s][nio][3] *= sfj[3];
        }
      }
      float rs = 0.f;
#pragma unroll
      for (int ni = 0; ni < 4; ++ni)
#pragma unroll
        for (int j = 0; j < 4; ++j) { float pv = fexp2(sc[ni][j] - mrow[s]); sc[ni][j] = pv; rs += pv; }
      rs += __shfl_xor(rs, 16); rs += __shfl_xor(rs, 32);
      lrow[s] += rs;
#pragma unroll
      for (int ni = 0; ni < 4; ++ni) {
        fp16x2 p0 = __builtin_amdgcn_cvt_pkrtz(sc[ni][0], sc[ni][1]);
        fp16x2 p1 = __builtin_amdgcn_cvt_pkrtz(sc[ni][2], sc[ni][3]);
        u[s][ni][0] = *(uint32_t*)&p0;
        u[s][ni][1] = *(uint32_t*)&p1;
      }
    }
    // ---- drain V[kt] (counted: leaves the 4 newer K[kt+1] loads in flight)
    if (kt + 1 < NT) { VM4(); } else { VM0(); }
    SBAR();   // barrier B: all waves' V[kt] visible in Vsh
    // ---- redistribute P into PV A-fragments; one bv read feeds both sub-tiles
#pragma unroll
    for (int kk = 0; kk < 2; ++kk) {
      half8v pa[2];
#pragma unroll
      for (int s = 0; s < 2; ++s) {
        uint32_t own0 = gbit ? u[s][2*kk+1][0] : u[s][2*kk][0];
        uint32_t own1 = gbit ? u[s][2*kk+1][1] : u[s][2*kk][1];
        uint32_t oth0 = gbit ? u[s][2*kk][0]   : u[s][2*kk+1][0];
        uint32_t oth1 = gbit ? u[s][2*kk][1]   : u[s][2*kk+1][1];
        uint32_t r16_0 = (uint32_t)__shfl_xor((int)own0, 16);
        uint32_t r16_1 = (uint32_t)__shfl_xor((int)own1, 16);
        uint32_t r32_0 = (uint32_t)__shfl_xor((int)oth0, 32);
        uint32_t r32_1 = (uint32_t)__shfl_xor((int)oth1, 32);
        uint32_t r48_0 = (uint32_t)__shfl_xor((int)oth0, 48);
        uint32_t r48_1 = (uint32_t)__shfl_xor((int)oth1, 48);
        uint32_t d0 = (g == 0) ? own0 : (g == 1) ? r48_0 : (g == 2) ? r32_0 : r16_0;
        uint32_t d1 = (g == 0) ? own1 : (g == 1) ? r48_1 : (g == 2) ? r32_1 : r16_1;
        uint32_t d2 = (g == 0) ? r16_0 : (g == 1) ? r32_0 : (g == 2) ? r48_0 : own0;
        uint32_t d3 = (g == 0) ? r16_1 : (g == 1) ? r32_1 : (g == 2) ? r48_1 : own1;
        union { uint32_t u4[4]; half8v hh; } pu;
        pu.u4[0] = d0; pu.u4[1] = d1; pu.u4[2] = d2; pu.u4[3] = d3;
        pa[s] = pu.hh;
      }
      __builtin_amdgcn_s_setprio(1);
#pragma unroll
      for (int nio = 0; nio < 8; ++nio) {
        int r = nio * 16 + li;
        int key = ((r >> 3) ^ r) & 7;
        half8v bv = *(const half8v*)(Vsh + r * 128 + (((kk * 4 + g) ^ key) << 4));
        oacc[0][nio] = __builtin_amdgcn_mfma_f32_16x16x32_f16(pa[0], bv, oacc[0][nio], 0, 0, 0);
        oacc[1][nio] = __builtin_amdgcn_mfma_f32_16x16x32_f16(pa[1], bv, oacc[1][nio], 0, 0, 0);
      }
      __builtin_amdgcn_s_setprio(0);
    }
    // ---- drain own K[kt+1]; barrier A: all done PV reads, K visible
    VM0();
    SBAR();
    // ---- issue V[kt+1] into the now-free Vsh (covered by next QK+softmax)
    if (kt + 1 < NT) ASTAGE_V(kt + 1, Vsh);
  }
#undef ASTAGE_K
#undef ASTAGE_V
  // ---- epilogue: O[q=4g+j][hd=16nio+li] / l[q], per sub-tile
#pragma unroll
  for (int s = 0; s < 2; ++s) {
    float rinv[4];
#pragma unroll
    for (int j = 0; j < 4; ++j)
      rinv[j] = 1.0f / __shfl(lrow[s], (lane & 48) | (4 * g + j));
    _Float16* Ob = Oa + (size_t)(b * SEQ + qt * 128 + w * 32 + s * 16) * DIM + h * HDIM;
#pragma unroll
    for (int j = 0; j < 4; ++j)
#pragma unroll
      for (int nio = 0; nio < 8; ++nio)
        Ob[(size_t)(4 * g + j) * DIM + nio * 16 + li] = (_Float16)(oacc[s][nio][j] * rinv[j]);
  }
}

// ---------------- launcher ----------------
extern "C" void kernel_launch(void* const* d_in, const int* in_sizes, int n_in,
                              void* d_out, int out_size, void* d_ws, size_t ws_size,
                              hipStream_t stream) {
  const float* x   = (const float*)d_in[0];
  const float* fc  = (const float*)d_in[1];
  const float* wq  = (const float*)d_in[2];
  const float* wk  = (const float*)d_in[3];
  const float* wv  = (const float*)d_in[4];
  const float* wo  = (const float*)d_in[5];
  const float* qnw = (const float*)d_in[6];
  const float* qnb = (const float*)d_in[7];
  const float* knw = (const float*)d_in[8];
  const float* knb = (const float*)d_in[9];
  float* out = (float*)d_out;
  (void)in_sizes; (void)n_in; (void)out_size;

  const size_t MB = 1024 * 1024;
  if (ws_size < 128 * MB) return;
  char* ws = (char*)d_ws;
  _Float16* x_h    = (_Float16*)(ws + 0);        // 32 MB [4096,4096]
  _Float16* wqkv_h = (_Float16*)(ws + 32 * MB);  // 48 MB [6144,4096] (wq|wk|wv)
  _Float16* qkv_h  = (_Float16*)(ws + 80 * MB);  // 40 MB [4096,5120] (q|k)
  _Float16* vt_h   = (_Float16*)(ws + 120 * MB); // 8 MB VT[b,kvh,hd,s]
  _Float16* wo_h   = wqkv_h;                     // 32 MB, reuse after QKV GEMM
  _Float16* ao_h   = x_h;                        // reuse after QKV GEMM

  cvt_kernel<<<2048, 256, 0, stream>>>(x, x_h, (MROWS * DIM) / 8);
  // wq|wk|wv -> contiguous wqkv_h in ONE launch
  cvt3_kernel<<<2048, 256, 0, stream>>>(wq, wk, wv, wqkv_h);

  // QKV GEMM: grid 256 perfect fill; Q|K -> qkv_h (stride 5120), V -> vt_h transposed
  gemm_qkv<<<256, 512, 0, stream>>>(x_h, wqkv_h, qkv_h, vt_h);

  cvt_kernel<<<2048, 256, 0, stream>>>(wo, wo_h, (DIM * DIM) / 8);

  // fused LN+RoPE for Q (scaled by 1/sqrt(HD)*log2e) and K, one launch
  const float qscale = (float)(0.08838834764831845 * 1.4426950408889634);
  ln_rope_fused<<<2 * MROWS, 256, 0, stream>>>(qkv_h, qnw, qnb, knw, knb, fc, qscale);

  // QBLK=128 (4 waves x 2 sub-tiles): grid = B * H * S/128 = 1024
  attn_kernel<<<NBATCH * NHEAD * (SEQ / 128), 256, 0, stream>>>(qkv_h, vt_h, ao_h);

  // out proj: M=4096, N=4096, K=4096 -> grid 16*16 = 256 = 1 full wave
  gemm256<0><<<(MROWS / 256) * (DIM / 256), 512, 0, stream>>>(ao_h, wo_h, out,
                                                              DIM, DIM, DIM / 256);
}